// Round 1
// baseline (165.358 us; speedup 1.0000x reference)
//
#include <hip/hip_runtime.h>
#include <stdint.h>

// ---------------------------------------------------------------------------
// HeteNet round 3: LOCAL expert sort (no global bucketing kernels).
// Each block owns 128 consecutive tokens (= one timestep, A=128), ballot-
// partitions them by expert into 16-row-padded groups, then runs the fused
// bf16 MFMA 3-layer MLP (expert + critic) on up to 11 tiles.
// Kernels: prep (weight fragments) -> main. ws holds only wp.
// ---------------------------------------------------------------------------

typedef float v4f __attribute__((ext_vector_type(4)));
typedef short v8s __attribute__((ext_vector_type(8)));

#define XS_STR 104   // LDS x stride (elems), 208 B (16B-aligned rows)
#define HS_STR 136   // LDS h stride (elems), 272 B (16B-aligned rows)
#define MAXR   176   // worst-case padded rows: 128 + 3*16
#define MAXT   11    // worst-case tiles
#define WP2_OFF 30720  // 60 frag-blocks * 512 shorts
#define WP3_OFF 51200  // + 40 * 512

#define SEL4(te, a0, a1, a2, a3) \
    ((te) < 2 ? ((te) == 0 ? (a0) : (a1)) : ((te) == 2 ? (a2) : (a3)))

static __device__ __forceinline__ short f2bf(float f) {
    union { float f; uint32_t u; } c; c.f = f;
    uint32_t u = c.u;
    uint32_t r = (u + 0x7FFFu + ((u >> 16) & 1u)) >> 16;
    return (short)r;
}

// ---------------- weight prep: B-fragment-ready bf16 layout ----------------
__global__ void prep_kernel(const float* __restrict__ W1, const float* __restrict__ cW1,
                            const float* __restrict__ W2, const float* __restrict__ cW2,
                            const float* __restrict__ W3, const float* __restrict__ cW3,
                            short* __restrict__ wp) {
    int b = blockIdx.x, lane = threadIdx.x;
    int nl = lane & 15, quad = lane >> 4;
    short frag[8];
    if (b < 60) {
        int e = b / 12, rem = b % 12, ks = rem / 4, nt = rem % 4;
        int n = nt * 16 + nl;
#pragma unroll
        for (int j = 0; j < 8; j++) {
            int k = ks * 32 + quad * 8 + j;
            float v = 0.f;
            if (k < 68) v = (e < 4) ? W1[(e * 68 + k) * 64 + n] : cW1[k * 64 + n];
            frag[j] = f2bf(v);
        }
    } else if (b < 100) {
        int u = b - 60, e = u / 8, ks = (u % 8) / 4, nt = u % 4;
        int n = nt * 16 + nl;
#pragma unroll
        for (int j = 0; j < 8; j++) {
            int k = ks * 32 + quad * 8 + j;
            frag[j] = f2bf((e < 4) ? W2[(e * 64 + k) * 64 + n] : cW2[k * 64 + n]);
        }
    } else {
        int u = b - 100;
#pragma unroll
        for (int j = 0; j < 8; j++) {
            int ks = (u < 8) ? (u & 1) : (u - 8);
            int k  = ks * 32 + quad * 8 + j;
            float v;
            if (u < 8) { int ee = u >> 1; v = W3[(ee * 64 + k) * 16 + nl]; }
            else       { v = (nl == 0) ? cW3[k] : 0.f; }
            frag[j] = f2bf(v);
        }
    }
    v8s pk = { frag[0], frag[1], frag[2], frag[3], frag[4], frag[5], frag[6], frag[7] };
    *(v8s*)(wp + (size_t)b * 512 + lane * 8) = pk;
}

// ---------------- fused main kernel (local sort + 3-layer MLP) ----------------

__global__ __launch_bounds__(256, 3) void main_kernel(
    const float* __restrict__ obs, const int* __restrict__ hete,
    const float* __restrict__ gp, const short* __restrict__ wp,
    const float* __restrict__ b1, const float* __restrict__ b2, const float* __restrict__ b3,
    const float* __restrict__ cb1, const float* __restrict__ cb2, const float* __restrict__ cb3,
    float* __restrict__ out)
{
    // union buffer: xs phase (stride XS_STR) then hs phase (stride HS_STR),
    // barrier-separated. 176*136*2 = 47872 B.
    __shared__ __align__(16) short buf[MAXR * HS_STR];
    __shared__ int rowtok[MAXR];   // row -> local token (or -1 = pad)
    __shared__ int tslot[128];     // local token -> row
    __shared__ int wcnt[2][4];     // per-wave expert counts

    short* xs = buf;
    short* hs = buf;

    const int b = blockIdx.x;
    const int tid = threadIdx.x, lane = tid & 63, w = tid >> 6;
    const int ml = lane & 15, quad = lane >> 4;
    const int col = w * 16 + ml;          // output column within N=64
    const size_t base = (size_t)b * 128;  // first token of this block

    // --- issue obs loads immediately (coalesced, contiguous 32 KB/block) ---
    const int ltk = tid >> 1, hh = tid & 1;   // 2 threads per token, 32 floats each
    const float4* src = (const float4*)(obs + (base + ltk) * 64 + hh * 32);
    float4 f[8];
#pragma unroll
    for (int t = 0; t < 8; t++) f[t] = src[t];

    // gp row is block-uniform (A = 128 tokens per timestep == tokens per block)
    const float* gpb = gp + (size_t)b * 4;
    float g0 = gpb[0], g1 = gpb[1], g2 = gpb[2], g3 = gpb[3];

    // --- local 4-way partition of 128 tokens (waves 0,1) ---
    if (tid < MAXR) rowtok[tid] = -1;

    int e = 0, rank = 0;
    if (tid < 128) {
        e = hete[base + tid];
        unsigned long long ltm = (1ull << lane) - 1ull;
        unsigned long long m0 = __ballot(e == 0);
        unsigned long long m1 = __ballot(e == 1);
        unsigned long long m2 = __ballot(e == 2);
        unsigned long long m3 = __ballot(e == 3);
        if      (e == 0) rank = __popcll(m0 & ltm);
        else if (e == 1) rank = __popcll(m1 & ltm);
        else if (e == 2) rank = __popcll(m2 & ltm);
        else             rank = __popcll(m3 & ltm);
        if (lane == 0) {
            wcnt[w][0] = __popcll(m0); wcnt[w][1] = __popcll(m1);
            wcnt[w][2] = __popcll(m2); wcnt[w][3] = __popcll(m3);
        }
    }
    __syncthreads();

    // group geometry (computed redundantly by every thread; all block-uniform)
    int c0 = wcnt[0][0] + wcnt[1][0];
    int c1 = wcnt[0][1] + wcnt[1][1];
    int c2 = wcnt[0][2] + wcnt[1][2];
    int c3 = wcnt[0][3] + wcnt[1][3];
    int p0 = (c0 + 15) & ~15, p1 = (c1 + 15) & ~15;
    int p2 = (c2 + 15) & ~15, p3 = (c3 + 15) & ~15;
    int gs1 = p0, gs2 = p0 + p1, gs3 = p0 + p1 + p2;
    int padded = gs3 + p3;
    int ntiles = padded >> 4;                 // 8..11, block-uniform
    // 2-bit expert id per tile, packed (<= 22 bits). 0x5555... & mask gives
    // the 2-bit value 01 repeated n times; *2 / *3 give experts 2/3.
    int n1 = p1 >> 4, n2 = p2 >> 4, n3 = p3 >> 4;
    int t1 = gs1 >> 4, t2 = gs2 >> 4, t3 = gs3 >> 4;
    int epack = ((0x55555555 & ((1 << (2 * n1)) - 1)) * 1) << (2 * t1)
              | ((0x55555555 & ((1 << (2 * n2)) - 1)) * 2) << (2 * t2)
              | ((0x55555555 & ((1 << (2 * n3)) - 1)) * 3) << (2 * t3);

    if (tid < 128) {
        int gsE  = SEL4(e, 0, gs1, gs2, gs3);
        int woff = (w == 1) ? wcnt[0][e] : 0;
        int slot = gsE + woff + rank;
        rowtok[slot] = tid;
        tslot[tid]   = slot;
    }
    __syncthreads();

    // --- stage x tile (sorted rows): obs | gp | zero-pad to 96 cols ---
    {
        v8s z = { 0, 0, 0, 0, 0, 0, 0, 0 };
        int s = tslot[ltk];
        int rb = s * XS_STR + hh * 32;
#pragma unroll
        for (int t = 0; t < 4; t++) {
            float4 a0 = f[2 * t], a1 = f[2 * t + 1];
            v8s pk = { f2bf(a0.x), f2bf(a0.y), f2bf(a0.z), f2bf(a0.w),
                       f2bf(a1.x), f2bf(a1.y), f2bf(a1.z), f2bf(a1.w) };
            *(v8s*)&xs[rb + t * 8] = pk;
        }
        if (hh) {
            v8s pg = { f2bf(g0), f2bf(g1), f2bf(g2), f2bf(g3), 0, 0, 0, 0 };
            *(v8s*)&xs[s * XS_STR + 64] = pg;
            *(v8s*)&xs[s * XS_STR + 72] = z;
            *(v8s*)&xs[s * XS_STR + 80] = z;
            *(v8s*)&xs[s * XS_STR + 88] = z;
        }
        // zero the padding rows (group tails)
#pragma unroll
        for (int p = 0; p < 2; p++) {
            int r = p * 128 + ltk;
            if (r < padded && rowtok[r] < 0) {
#pragma unroll
                for (int t = 0; t < 4; t++) *(v8s*)&xs[r * XS_STR + hh * 32 + t * 8] = z;
                if (hh) {
                    *(v8s*)&xs[r * XS_STR + 64] = z;
                    *(v8s*)&xs[r * XS_STR + 72] = z;
                    *(v8s*)&xs[r * XS_STR + 80] = z;
                    *(v8s*)&xs[r * XS_STR + 88] = z;
                }
            }
        }
    }
    __syncthreads();

    // --- layer 1: [rows x 96] @ [96 x 64], expert (per-tile) + critic fused ---
    v4f accE[MAXT], accC[MAXT];
#pragma unroll
    for (int mt = 0; mt < MAXT; mt++) { accE[mt] = (v4f){0,0,0,0}; accC[mt] = (v4f){0,0,0,0}; }

    v8s bC1f[3];
#pragma unroll
    for (int ks = 0; ks < 3; ks++)
        bC1f[ks] = *(const v8s*)(wp + (size_t)((12 + ks) * 4 + w) * 512 + lane * 8);

#pragma unroll
    for (int ks = 0; ks < 3; ks++) {
#pragma unroll
        for (int mt = 0; mt < MAXT; mt++) {
            if (mt < ntiles) {   // block-uniform guard; acc stays statically indexed
                int te = (epack >> (2 * mt)) & 3;
                v8s bE = *(const v8s*)(wp + (size_t)((te * 3 + ks) * 4 + w) * 512 + lane * 8);
                v8s a  = *(const v8s*)&xs[(mt * 16 + ml) * XS_STR + ks * 32 + quad * 8];
                accE[mt] = __builtin_amdgcn_mfma_f32_16x16x32_bf16(a, bE,       accE[mt], 0, 0, 0);
                accC[mt] = __builtin_amdgcn_mfma_f32_16x16x32_bf16(a, bC1f[ks], accC[mt], 0, 0, 0);
            }
        }
    }
    __syncthreads();  // xs reads complete before hs overwrites (union buffer)

    {
        float b1e0 = b1[col], b1e1 = b1[64 + col], b1e2 = b1[128 + col], b1e3 = b1[192 + col];
        float cb1v = cb1[col];
#pragma unroll
        for (int mt = 0; mt < MAXT; mt++) {
            if (mt < ntiles) {
                int te = (epack >> (2 * mt)) & 3;
                float bv = SEL4(te, b1e0, b1e1, b1e2, b1e3);
#pragma unroll
                for (int rr = 0; rr < 4; rr++) {
                    int row = mt * 16 + quad * 4 + rr;
                    hs[row * HS_STR + col]      = f2bf(fmaxf(accE[mt][rr] + bv,   0.f));
                    hs[row * HS_STR + 64 + col] = f2bf(fmaxf(accC[mt][rr] + cb1v, 0.f));
                }
            }
        }
    }
    __syncthreads();

    // --- layer 2: [rows x 64] @ [64 x 64] for both nets ---
    v4f acc2E[MAXT], acc2C[MAXT];
#pragma unroll
    for (int mt = 0; mt < MAXT; mt++) { acc2E[mt] = (v4f){0,0,0,0}; acc2C[mt] = (v4f){0,0,0,0}; }

    v8s bC2f[2];
#pragma unroll
    for (int ks = 0; ks < 2; ks++)
        bC2f[ks] = *(const v8s*)(wp + WP2_OFF + (size_t)((8 + ks) * 4 + w) * 512 + lane * 8);

#pragma unroll
    for (int ks = 0; ks < 2; ks++) {
#pragma unroll
        for (int mt = 0; mt < MAXT; mt++) {
            if (mt < ntiles) {
                int te = (epack >> (2 * mt)) & 3;
                v8s bE = *(const v8s*)(wp + WP2_OFF + (size_t)((te * 2 + ks) * 4 + w) * 512 + lane * 8);
                v8s aE = *(const v8s*)&hs[(mt * 16 + ml) * HS_STR + ks * 32 + quad * 8];
                v8s aC = *(const v8s*)&hs[(mt * 16 + ml) * HS_STR + 64 + ks * 32 + quad * 8];
                acc2E[mt] = __builtin_amdgcn_mfma_f32_16x16x32_bf16(aE, bE,       acc2E[mt], 0, 0, 0);
                acc2C[mt] = __builtin_amdgcn_mfma_f32_16x16x32_bf16(aC, bC2f[ks], acc2C[mt], 0, 0, 0);
            }
        }
    }
    __syncthreads();  // all h1 reads complete before overwrite

    {
        float b2e0 = b2[col], b2e1 = b2[64 + col], b2e2 = b2[128 + col], b2e3 = b2[192 + col];
        float cb2v = cb2[col];
#pragma unroll
        for (int mt = 0; mt < MAXT; mt++) {
            if (mt < ntiles) {
                int te = (epack >> (2 * mt)) & 3;
                float bv = SEL4(te, b2e0, b2e1, b2e2, b2e3);
#pragma unroll
                for (int rr = 0; rr < 4; rr++) {
                    int row = mt * 16 + quad * 4 + rr;
                    hs[row * HS_STR + col]      = f2bf(fmaxf(acc2E[mt][rr] + bv,   0.f));
                    hs[row * HS_STR + 64 + col] = f2bf(fmaxf(acc2C[mt][rr] + cb2v, 0.f));
                }
            }
        }
    }
    __syncthreads();

    // --- layer 3: waves split tiles {w, w+4, w+8}; expert [16x64]@[64x16],
    //     critic value via padded N=16 ---
    v4f accL[3], accV[3];
#pragma unroll
    for (int j = 0; j < 3; j++) { accL[j] = (v4f){0,0,0,0}; accV[j] = (v4f){0,0,0,0}; }

#pragma unroll
    for (int ks = 0; ks < 2; ks++) {
        v8s bV = *(const v8s*)(wp + WP3_OFF + (size_t)(8 + ks) * 512 + lane * 8);
#pragma unroll
        for (int j = 0; j < 3; j++) {
            int mt = w + 4 * j;
            if (mt < ntiles) {   // wave-uniform guard
                int te = (epack >> (2 * mt)) & 3;
                v8s bW = *(const v8s*)(wp + WP3_OFF + (size_t)(te * 2 + ks) * 512 + lane * 8);
                v8s aE = *(const v8s*)&hs[(mt * 16 + ml) * HS_STR + ks * 32 + quad * 8];
                v8s aC = *(const v8s*)&hs[(mt * 16 + ml) * HS_STR + 64 + ks * 32 + quad * 8];
                accL[j] = __builtin_amdgcn_mfma_f32_16x16x32_bf16(aE, bW, accL[j], 0, 0, 0);
                accV[j] = __builtin_amdgcn_mfma_f32_16x16x32_bf16(aC, bV, accV[j], 0, 0, 0);
            }
        }
    }

    // --- epilogue: out[token][0..15] = logits, out[token][16] = value ---
    {
        float b3e0 = b3[ml], b3e1 = b3[16 + ml], b3e2 = b3[32 + ml], b3e3 = b3[48 + ml];
        float cb3v = cb3[0];
#pragma unroll
        for (int j = 0; j < 3; j++) {
            int mt = w + 4 * j;
            if (mt < ntiles) {
                int te = (epack >> (2 * mt)) & 3;
                float bv = SEL4(te, b3e0, b3e1, b3e2, b3e3);
#pragma unroll
                for (int rr = 0; rr < 4; rr++) {
                    int r = mt * 16 + quad * 4 + rr;
                    int tk = rowtok[r];
                    if (tk >= 0) {
                        float* o = out + (base + tk) * 17;
                        o[ml] = accL[j][rr] + bv;
                        if (ml == 0) o[16] = accV[j][rr] + cb3v;
                    }
                }
            }
        }
    }
}

// ---------------------------------------------------------------------------

extern "C" void kernel_launch(void* const* d_in, const int* in_sizes, int n_in,
                              void* d_out, int out_size, void* d_ws, size_t ws_size,
                              hipStream_t stream) {
    const float* obs = (const float*)d_in[0];
    const int*  hete = (const int*)d_in[1];
    const float* gp  = (const float*)d_in[2];
    const float* W1  = (const float*)d_in[3];
    const float* b1  = (const float*)d_in[4];
    const float* W2  = (const float*)d_in[5];
    const float* b2  = (const float*)d_in[6];
    const float* W3  = (const float*)d_in[7];
    const float* b3  = (const float*)d_in[8];
    const float* cW1 = (const float*)d_in[9];
    const float* cb1 = (const float*)d_in[10];
    const float* cW2 = (const float*)d_in[11];
    const float* cb2 = (const float*)d_in[12];
    const float* cW3 = (const float*)d_in[13];
    const float* cb3 = (const float*)d_in[14];
    float* out = (float*)d_out;

    short* wp = (short*)d_ws;   // 110 * 512 shorts = 112640 B

    prep_kernel<<<110,  64, 0, stream>>>(W1, cW1, W2, cW2, W3, cW3, wp);
    main_kernel<<<2048, 256, 0, stream>>>(obs, hete, gp, wp,
                                          b1, b2, b3, cb1, cb2, cb3, out);
}

// Round 3
// 158.052 us; speedup vs baseline: 1.0462x; 1.0462x over previous
//
#include <hip/hip_runtime.h>
#include <stdint.h>

// ---------------------------------------------------------------------------
// HeteNet round 5 (= audited round-4 design, resubmitted after infra failure):
// local sort WITHOUT padding (128 rows, 8 tiles exactly), boundary-straddle
// tiles handled by <=3 fix-up MFMA chains per layer.
// Transposed dataflow: mfma(A=W_frag, B=x_frag) -> D=(XW)^T, so each lane
// holds 4 consecutive features of ONE token: packed b64 LDS h-writes,
// float4 bias loads, dwordx4 logits stores. Native __bf16 conversions
// (RNE, identical numerics to manual round-0 path).
// Kernels: prep -> main. ws holds only wp.
// ---------------------------------------------------------------------------

typedef float v4f __attribute__((ext_vector_type(4)));
typedef short v8s __attribute__((ext_vector_type(8)));
typedef short v4s __attribute__((ext_vector_type(4)));
typedef float v4fa __attribute__((ext_vector_type(4), aligned(4)));

#define HS_STR 136     // LDS row stride (elems), 272 B (16B-aligned rows)
#define WP2_OFF 30720  // 60 frag-blocks * 512 shorts
#define WP3_OFF 51200  // + 40 * 512

#define SEL4(te, a0, a1, a2, a3) \
    ((te) < 2 ? ((te) == 0 ? (a0) : (a1)) : ((te) == 2 ? (a2) : (a3)))

static __device__ __forceinline__ short f2bf(float f) {
    union { __bf16 b; short s; } u;
    u.b = (__bf16)f;   // native RNE convert (scalar cast is the fast path on gfx950)
    return u.s;
}

static __device__ __forceinline__ v4s pack4_relu(const v4f a, const v4fa bias) {
    v4s r;
    r[0] = f2bf(fmaxf(a[0] + bias[0], 0.f));
    r[1] = f2bf(fmaxf(a[1] + bias[1], 0.f));
    r[2] = f2bf(fmaxf(a[2] + bias[2], 0.f));
    r[3] = f2bf(fmaxf(a[3] + bias[3], 0.f));
    return r;
}

// ---------------- weight prep: fragment-ready bf16 layout ----------------
// Stored per frag-block: lane l holds index n=l&15 (out-feat), k=(l>>4)*8+j.
// Identical per-lane layout for MFMA A- and B-operands, so these fragments
// serve directly as A (= W^T) in the transposed flow.
__global__ void prep_kernel(const float* __restrict__ W1, const float* __restrict__ cW1,
                            const float* __restrict__ W2, const float* __restrict__ cW2,
                            const float* __restrict__ W3, const float* __restrict__ cW3,
                            short* __restrict__ wp) {
    int b = blockIdx.x, lane = threadIdx.x;
    int nl = lane & 15, quad = lane >> 4;
    short frag[8];
    if (b < 60) {
        int e = b / 12, rem = b % 12, ks = rem / 4, nt = rem % 4;
        int n = nt * 16 + nl;
#pragma unroll
        for (int j = 0; j < 8; j++) {
            int k = ks * 32 + quad * 8 + j;
            float v = 0.f;
            if (k < 68) v = (e < 4) ? W1[(e * 68 + k) * 64 + n] : cW1[k * 64 + n];
            frag[j] = f2bf(v);
        }
    } else if (b < 100) {
        int u = b - 60, e = u / 8, ks = (u % 8) / 4, nt = u % 4;
        int n = nt * 16 + nl;
#pragma unroll
        for (int j = 0; j < 8; j++) {
            int k = ks * 32 + quad * 8 + j;
            frag[j] = f2bf((e < 4) ? W2[(e * 64 + k) * 64 + n] : cW2[k * 64 + n]);
        }
    } else {
        int u = b - 100;
#pragma unroll
        for (int j = 0; j < 8; j++) {
            int ks = (u < 8) ? (u & 1) : (u - 8);
            int k  = ks * 32 + quad * 8 + j;
            float v;
            if (u < 8) { int ee = u >> 1; v = W3[(ee * 64 + k) * 16 + nl]; }
            else       { v = (nl == 0) ? cW3[k] : 0.f; }
            frag[j] = f2bf(v);
        }
    }
    v8s pk = { frag[0], frag[1], frag[2], frag[3], frag[4], frag[5], frag[6], frag[7] };
    *(v8s*)(wp + (size_t)b * 512 + lane * 8) = pk;
}

// ---------------- fused main kernel ----------------

__global__ __launch_bounds__(256, 4) void main_kernel(
    const float* __restrict__ obs, const int* __restrict__ hete,
    const float* __restrict__ gp, const short* __restrict__ wp,
    const float* __restrict__ b1, const float* __restrict__ b2, const float* __restrict__ b3,
    const float* __restrict__ cb1, const float* __restrict__ cb2, const float* __restrict__ cb3,
    float* __restrict__ out)
{
    // union buffer: xs phase uses cols [0,96), hs phase uses cols [0,128).
    // 128 * 136 * 2 = 34816 B -> 4 blocks/CU.
    __shared__ __align__(16) short buf[128 * HS_STR];
    __shared__ int rowtok[128];   // sorted row -> local token
    __shared__ int tslot[128];    // local token -> sorted row
    __shared__ int wcnt[2][4];    // per-wave expert counts

    short* xs = buf;
    short* hs = buf;

    const int b = blockIdx.x;
    const int tid = threadIdx.x, lane = tid & 63, w = tid >> 6;
    const int ml = lane & 15, quad = lane >> 4;
    const size_t base = (size_t)b * 128;

    // --- issue obs loads immediately (coalesced contiguous 32 KB/block) ---
    const int ltk = tid >> 1, hh = tid & 1;   // 2 threads per token, 32 floats each
    const float4* src = (const float4*)(obs + (base + ltk) * 64 + hh * 32);
    float4 f[8];
#pragma unroll
    for (int t = 0; t < 8; t++) f[t] = src[t];

    // gp row is block-uniform (one timestep per block)
    const float* gpb = gp + (size_t)b * 4;
    float g0 = gpb[0], g1 = gpb[1], g2 = gpb[2], g3 = gpb[3];

    // --- 4-way stable partition of 128 tokens (waves 0,1), NO padding ---
    int e = 0, rank = 0;
    if (tid < 128) {
        e = hete[base + tid];
        unsigned long long ltm = (1ull << lane) - 1ull;
        unsigned long long m0 = __ballot(e == 0);
        unsigned long long m1 = __ballot(e == 1);
        unsigned long long m2 = __ballot(e == 2);
        unsigned long long m3 = __ballot(e == 3);
        if      (e == 0) rank = __popcll(m0 & ltm);
        else if (e == 1) rank = __popcll(m1 & ltm);
        else if (e == 2) rank = __popcll(m2 & ltm);
        else             rank = __popcll(m3 & ltm);
        if (lane == 0) {
            wcnt[w][0] = __popcll(m0); wcnt[w][1] = __popcll(m1);
            wcnt[w][2] = __popcll(m2); wcnt[w][3] = __popcll(m3);
        }
    }
    __syncthreads();

    // group starts (block-uniform)
    const int c0 = wcnt[0][0] + wcnt[1][0];
    const int c1 = wcnt[0][1] + wcnt[1][1];
    const int c2 = wcnt[0][2] + wcnt[1][2];
    const int gs1 = c0, gs2 = c0 + c1, gs3 = c0 + c1 + c2;

    if (tid < 128) {
        int gsE  = SEL4(e, 0, gs1, gs2, gs3);
        int woff = (w == 1) ? wcnt[0][e] : 0;
        int slot = gsE + woff + rank;
        rowtok[slot] = tid;
        tslot[tid]   = slot;
    }
    __syncthreads();

    // per-tile base expert (expert of the tile's first row); static indices only
    int teA[8];
#pragma unroll
    for (int mt = 0; mt < 8; mt++)
        teA[mt] = (mt * 16 >= gs1) + (mt * 16 >= gs2) + (mt * 16 >= gs3);

    // --- stage x tile (sorted rows): obs | gp | zero-pad cols 68..95 ---
    {
        int s  = tslot[ltk];
        int rb = s * HS_STR + hh * 32;
#pragma unroll
        for (int t = 0; t < 4; t++) {
            float4 a0 = f[2 * t], a1 = f[2 * t + 1];
            v8s pk = { f2bf(a0.x), f2bf(a0.y), f2bf(a0.z), f2bf(a0.w),
                       f2bf(a1.x), f2bf(a1.y), f2bf(a1.z), f2bf(a1.w) };
            *(v8s*)&xs[rb + t * 8] = pk;
        }
        if (hh) {
            v8s pg = { f2bf(g0), f2bf(g1), f2bf(g2), f2bf(g3), 0, 0, 0, 0 };
            v8s z8 = { 0, 0, 0, 0, 0, 0, 0, 0 };
            *(v8s*)&xs[s * HS_STR + 64] = pg;
            *(v8s*)&xs[s * HS_STR + 72] = z8;
            *(v8s*)&xs[s * HS_STR + 80] = z8;
            *(v8s*)&xs[s * HS_STR + 88] = z8;
        }
    }
    __syncthreads();

    // =====================================================================
    // Layer 1: D = W^T * X^T  (M=out-feat, N=token). Wave w covers feats
    // w*16..w*16+15. Lane holds 4 consecutive feats of token ml.
    // =====================================================================
    v4f accE[8], accC[8];
#pragma unroll
    for (int mt = 0; mt < 8; mt++) { accE[mt] = (v4f){0,0,0,0}; accC[mt] = (v4f){0,0,0,0}; }

    v8s cf1[3];
#pragma unroll
    for (int ks = 0; ks < 3; ks++)
        cf1[ks] = *(const v8s*)(wp + (size_t)((12 + ks) * 4 + w) * 512 + lane * 8);

#pragma unroll
    for (int ks = 0; ks < 3; ks++) {
#pragma unroll
        for (int mt = 0; mt < 8; mt++) {
            v8s aW = *(const v8s*)(wp + (size_t)((teA[mt] * 3 + ks) * 4 + w) * 512 + lane * 8);
            v8s xB = *(const v8s*)&xs[(mt * 16 + ml) * HS_STR + ks * 32 + quad * 8];
            accE[mt] = __builtin_amdgcn_mfma_f32_16x16x32_bf16(aW, xB, accE[mt], 0, 0, 0);
            accC[mt] = __builtin_amdgcn_mfma_f32_16x16x32_bf16(cf1[ks], xB, accC[mt], 0, 0, 0);
        }
    }

    // boundary fix-ups (<=3): straddle tile recomputed with the next expert
    v4f fx[3];
#pragma unroll
    for (int bb = 0; bb < 3; bb++) {
        fx[bb] = (v4f){0,0,0,0};
        int pos = (bb == 0) ? gs1 : (bb == 1) ? gs2 : gs3;
        if (pos & 15) {
            int mtb = pos >> 4, te = bb + 1;
#pragma unroll
            for (int ks = 0; ks < 3; ks++) {
                v8s aW = *(const v8s*)(wp + (size_t)((te * 3 + ks) * 4 + w) * 512 + lane * 8);
                v8s xB = *(const v8s*)&xs[(mtb * 16 + ml) * HS_STR + ks * 32 + quad * 8];
                fx[bb] = __builtin_amdgcn_mfma_f32_16x16x32_bf16(aW, xB, fx[bb], 0, 0, 0);
            }
        }
    }
    __syncthreads();  // all xs reads complete before hs overwrites (union)

    // h1 writes: packed b64 (4 consecutive feats of token ml)
    {
        v4fa cbv = *(const v4fa*)(cb1 + w * 16 + quad * 4);
#pragma unroll
        for (int mt = 0; mt < 8; mt++) {
            v4fa bv = *(const v4fa*)(b1 + teA[mt] * 64 + w * 16 + quad * 4);
            int rb = (mt * 16 + ml) * HS_STR + w * 16 + quad * 4;
            *(v4s*)&hs[rb]      = pack4_relu(accE[mt], bv);
            *(v4s*)&hs[rb + 64] = pack4_relu(accC[mt], cbv);
        }
        // fix-up overwrites (DS ops from the same wave are in-order: safe)
#pragma unroll
        for (int bb = 0; bb < 3; bb++) {
            int pos = (bb == 0) ? gs1 : (bb == 1) ? gs2 : gs3;
            if (pos & 15) {
                int mtb = pos >> 4, te = bb + 1;
                int row = mtb * 16 + ml;
                int erow = (row >= gs1) + (row >= gs2) + (row >= gs3);
                if (erow == te) {
                    v4fa bv = *(const v4fa*)(b1 + te * 64 + w * 16 + quad * 4);
                    *(v4s*)&hs[row * HS_STR + w * 16 + quad * 4] = pack4_relu(fx[bb], bv);
                }
            }
        }
    }
    __syncthreads();

    // =====================================================================
    // Layer 2: same transposed pattern, K=64 (2 ks steps)
    // =====================================================================
    v4f acc2E[8], acc2C[8];
#pragma unroll
    for (int mt = 0; mt < 8; mt++) { acc2E[mt] = (v4f){0,0,0,0}; acc2C[mt] = (v4f){0,0,0,0}; }

    v8s cf2[2];
#pragma unroll
    for (int ks = 0; ks < 2; ks++)
        cf2[ks] = *(const v8s*)(wp + WP2_OFF + (size_t)((8 + ks) * 4 + w) * 512 + lane * 8);

#pragma unroll
    for (int ks = 0; ks < 2; ks++) {
#pragma unroll
        for (int mt = 0; mt < 8; mt++) {
            v8s aW = *(const v8s*)(wp + WP2_OFF + (size_t)((teA[mt] * 2 + ks) * 4 + w) * 512 + lane * 8);
            v8s hE = *(const v8s*)&hs[(mt * 16 + ml) * HS_STR + ks * 32 + quad * 8];
            v8s hC = *(const v8s*)&hs[(mt * 16 + ml) * HS_STR + 64 + ks * 32 + quad * 8];
            acc2E[mt] = __builtin_amdgcn_mfma_f32_16x16x32_bf16(aW, hE, acc2E[mt], 0, 0, 0);
            acc2C[mt] = __builtin_amdgcn_mfma_f32_16x16x32_bf16(cf2[ks], hC, acc2C[mt], 0, 0, 0);
        }
    }

    v4f fx2[3];
#pragma unroll
    for (int bb = 0; bb < 3; bb++) {
        fx2[bb] = (v4f){0,0,0,0};
        int pos = (bb == 0) ? gs1 : (bb == 1) ? gs2 : gs3;
        if (pos & 15) {
            int mtb = pos >> 4, te = bb + 1;
#pragma unroll
            for (int ks = 0; ks < 2; ks++) {
                v8s aW = *(const v8s*)(wp + WP2_OFF + (size_t)((te * 2 + ks) * 4 + w) * 512 + lane * 8);
                v8s hE = *(const v8s*)&hs[(mtb * 16 + ml) * HS_STR + ks * 32 + quad * 8];
                fx2[bb] = __builtin_amdgcn_mfma_f32_16x16x32_bf16(aW, hE, fx2[bb], 0, 0, 0);
            }
        }
    }
    __syncthreads();  // all h1 reads complete before h2 overwrites

    {
        v4fa cbv = *(const v4fa*)(cb2 + w * 16 + quad * 4);
#pragma unroll
        for (int mt = 0; mt < 8; mt++) {
            v4fa bv = *(const v4fa*)(b2 + teA[mt] * 64 + w * 16 + quad * 4);
            int rb = (mt * 16 + ml) * HS_STR + w * 16 + quad * 4;
            *(v4s*)&hs[rb]      = pack4_relu(acc2E[mt], bv);
            *(v4s*)&hs[rb + 64] = pack4_relu(acc2C[mt], cbv);
        }
#pragma unroll
        for (int bb = 0; bb < 3; bb++) {
            int pos = (bb == 0) ? gs1 : (bb == 1) ? gs2 : gs3;
            if (pos & 15) {
                int mtb = pos >> 4, te = bb + 1;
                int row = mtb * 16 + ml;
                int erow = (row >= gs1) + (row >= gs2) + (row >= gs3);
                if (erow == te) {
                    v4fa bv = *(const v4fa*)(b2 + te * 64 + w * 16 + quad * 4);
                    *(v4s*)&hs[row * HS_STR + w * 16 + quad * 4] = pack4_relu(fx2[bb], bv);
                }
            }
        }
    }
    __syncthreads();

    // =====================================================================
    // Layer 3: wave w owns tiles {w, w+4}. M=16 logits; critic value via
    // padded M (row 0 only). Lane holds 4 consecutive logits of token ml.
    // =====================================================================
    v4f accL[2], accV[2];
#pragma unroll
    for (int j = 0; j < 2; j++) { accL[j] = (v4f){0,0,0,0}; accV[j] = (v4f){0,0,0,0}; }

#pragma unroll
    for (int ks = 0; ks < 2; ks++) {
        v8s aV = *(const v8s*)(wp + WP3_OFF + (size_t)(8 + ks) * 512 + lane * 8);
#pragma unroll
        for (int j = 0; j < 2; j++) {
            int mt = w + 4 * j;
            int te = (mt * 16 >= gs1) + (mt * 16 >= gs2) + (mt * 16 >= gs3);
            v8s aW = *(const v8s*)(wp + WP3_OFF + (size_t)(te * 2 + ks) * 512 + lane * 8);
            v8s hE = *(const v8s*)&hs[(mt * 16 + ml) * HS_STR + ks * 32 + quad * 8];
            v8s hC = *(const v8s*)&hs[(mt * 16 + ml) * HS_STR + 64 + ks * 32 + quad * 8];
            accL[j] = __builtin_amdgcn_mfma_f32_16x16x32_bf16(aW, hE, accL[j], 0, 0, 0);
            accV[j] = __builtin_amdgcn_mfma_f32_16x16x32_bf16(aV, hC, accV[j], 0, 0, 0);
        }
    }

    v4f fxL[3];
#pragma unroll
    for (int bb = 0; bb < 3; bb++) {
        fxL[bb] = (v4f){0,0,0,0};
        int pos = (bb == 0) ? gs1 : (bb == 1) ? gs2 : gs3;
        int mtb = pos >> 4;
        if ((pos & 15) && (mtb & 3) == w) {
            int te = bb + 1;
#pragma unroll
            for (int ks = 0; ks < 2; ks++) {
                v8s aW = *(const v8s*)(wp + WP3_OFF + (size_t)(te * 2 + ks) * 512 + lane * 8);
                v8s hE = *(const v8s*)&hs[(mtb * 16 + ml) * HS_STR + ks * 32 + quad * 8];
                fxL[bb] = __builtin_amdgcn_mfma_f32_16x16x32_bf16(aW, hE, fxL[bb], 0, 0, 0);
            }
        }
    }

    // --- epilogue: dwordx4 logits store + value. Base store predicated on
    //     erow==te so fix-up is the only writer for straddled tokens (global
    //     store-order to same address is not guaranteed, unlike DS). ---
    {
        float cb3v = cb3[0];
#pragma unroll
        for (int j = 0; j < 2; j++) {
            int mt = w + 4 * j;
            int te = (mt * 16 >= gs1) + (mt * 16 >= gs2) + (mt * 16 >= gs3);
            int row = mt * 16 + ml;
            int erow = (row >= gs1) + (row >= gs2) + (row >= gs3);
            int tk = rowtok[row];
            float* o = out + (base + (size_t)tk) * 17;
            if (erow == te) {
                v4fa b3v = *(const v4fa*)(b3 + te * 16 + quad * 4);
                v4fa ov = { accL[j][0] + b3v[0], accL[j][1] + b3v[1],
                            accL[j][2] + b3v[2], accL[j][3] + b3v[3] };
                *(v4fa*)(o + quad * 4) = ov;
            }
            if (quad == 0) o[16] = accV[j][0] + cb3v;
        }
#pragma unroll
        for (int bb = 0; bb < 3; bb++) {
            int pos = (bb == 0) ? gs1 : (bb == 1) ? gs2 : gs3;
            int mtb = pos >> 4;
            if ((pos & 15) && (mtb & 3) == w) {
                int row = mtb * 16 + ml;
                int erow = (row >= gs1) + (row >= gs2) + (row >= gs3);
                if (erow == bb + 1) {
                    v4fa b3v = *(const v4fa*)(b3 + (bb + 1) * 16 + quad * 4);
                    int tk = rowtok[row];
                    float* o = out + (base + (size_t)tk) * 17;
                    v4fa ov = { fxL[bb][0] + b3v[0], fxL[bb][1] + b3v[1],
                                fxL[bb][2] + b3v[2], fxL[bb][3] + b3v[3] };
                    *(v4fa*)(o + quad * 4) = ov;
                }
            }
        }
    }
}

// ---------------------------------------------------------------------------

extern "C" void kernel_launch(void* const* d_in, const int* in_sizes, int n_in,
                              void* d_out, int out_size, void* d_ws, size_t ws_size,
                              hipStream_t stream) {
    const float* obs = (const float*)d_in[0];
    const int*  hete = (const int*)d_in[1];
    const float* gp  = (const float*)d_in[2];
    const float* W1  = (const float*)d_in[3];
    const float* b1  = (const float*)d_in[4];
    const float* W2  = (const float*)d_in[5];
    const float* b2  = (const float*)d_in[6];
    const float* W3  = (const float*)d_in[7];
    const float* b3  = (const float*)d_in[8];
    const float* cW1 = (const float*)d_in[9];
    const float* cb1 = (const float*)d_in[10];
    const float* cW2 = (const float*)d_in[11];
    const float* cb2 = (const float*)d_in[12];
    const float* cW3 = (const float*)d_in[13];
    const float* cb3 = (const float*)d_in[14];
    float* out = (float*)d_out;

    short* wp = (short*)d_ws;   // 110 * 512 shorts = 112640 B

    prep_kernel<<<110,  64, 0, stream>>>(W1, cW1, W2, cW2, W3, cW3, wp);
    main_kernel<<<2048, 256, 0, stream>>>(obs, hete, gp, wp,
                                          b1, b2, b3, cb1, cb2, cb3, out);
}